// Round 1
// 7795.985 us; speedup vs baseline: 1.0482x; 1.0482x over previous
//
#include <hip/hip_runtime.h>
#include <math.h>

// Problem constants
#define T_STEPS 1024
#define BATCH   32
#define HID     512
#define G4      2048          // 4*HID
#define KDIM    1024          // I + H (concat [x|h])
#define NWG     128           // total workgroups (64 per layer)
#define WGL     64            // WGs per layer
#define JPW     8             // h-columns owned per WG
#define APAD    1032          // Wbuf padded row stride (shorts)
#define FPAD    32            // flag stride in u32 (one 128B line per flag)

#define OUT_ELEMS   (BATCH * T_STEPS * HID)          // 16777216
#define H_OFF       OUT_ELEMS
#define C_OFF       (OUT_ELEMS + 2 * BATCH * HID)

typedef __attribute__((ext_vector_type(8)))  short short8;
typedef __attribute__((ext_vector_type(16))) float f32x16;

__device__ __forceinline__ unsigned short f2bf(float f) {
    union { float f; unsigned u; } v; v.f = f;
    unsigned r = v.u + 0x7fffu + ((v.u >> 16) & 1u);   // RNE
    return (unsigned short)(r >> 16);
}

__device__ __forceinline__ float sigm(float x)  { return 1.0f / (1.0f + __expf(-x)); }
__device__ __forceinline__ float ftanh(float x) { return 1.0f - 2.0f / (__expf(2.0f * x) + 1.0f); }

// ---- single-level direct-poll grid barrier ----
// Data protocol unchanged from the proven version: h rings written ONLY with
// agent-scope (sc1) stores -> never dirty in any L2; readers do a per-step
// agent acquire fence (buffer_inv) then PLAIN loads. Flags are agent-scope
// atomics, one per 128B line so 128 WGs x 128 lanes poll 128 distinct LLC
// lines (no slice hot-spot). Removing the WG0-aggregate/release hop cuts one
// dependent LLC round trip per step; the wait condition (all flags >= epoch)
// is identical to the old two-level barrier.
__device__ __forceinline__ void g_arrive(unsigned* flags, int wg, unsigned epoch, int tid) {
    asm volatile("s_waitcnt vmcnt(0)" ::: "memory");   // drain sc1 h-publishes
    __syncthreads();
    if (tid == 0)
        __hip_atomic_store(&flags[wg * FPAD], epoch, __ATOMIC_RELAXED, __HIP_MEMORY_SCOPE_AGENT);
}

__device__ __forceinline__ void g_wait(unsigned* flags, unsigned epoch, int tid) {
    if (tid < NWG) {
        while (__hip_atomic_load(&flags[tid * FPAD], __ATOMIC_RELAXED, __HIP_MEMORY_SCOPE_AGENT) < epoch)
            __builtin_amdgcn_s_sleep(1);
    }
    __syncthreads();
}

__global__ void init_flags(unsigned* flags) {
    for (int i = threadIdx.x; i < NWG * FPAD; i += 256) flags[i] = 0u;
}

// Per-WG GEMM restructure: one 32x32 output tile (32 batch x 32 gate-rows),
// K=1024 split across the 4 waves (256 each), mfma_f32_32x32x16_bf16.
// A-fragments (lane l: row=l&31, k=(l>>5)*8+i) are loaded DIRECTLY from
// global (xbf / h rings) into VGPRs -- no Abuf staging, no ds_writes, and
// 4x fewer ds_reads (B only). Partial 32x32 tiles reduced through gatebuf.
__global__ void __launch_bounds__(256, 1)
lstm_persist(const float* __restrict__ x_in,   // [32][1024][512]
             const float* __restrict__ h0,     // [2][32][512]
             const float* __restrict__ c0,     // [2][32][512]
             const float* __restrict__ Wih,    // [2][2048][512]
             const float* __restrict__ Whh,    // [2][2048][512]
             const float* __restrict__ bih,    // [2][2048]
             const float* __restrict__ bhh,    // [2][2048]
             float* __restrict__ out,
             unsigned* __restrict__ flags,
             unsigned short* __restrict__ h1ring,  // [2][32][512] bf16 (ws, sc1-written)
             unsigned short* __restrict__ h2ring,  // [2][32][512] bf16 (ws, sc1-written)
             unsigned short* __restrict__ xbf,     // [32][1024][512] bf16 (ws, plain)
             int use_xbf)
{
    __shared__ __attribute__((aligned(16))) short Wbuf[32 * APAD];
    __shared__ float gatebuf[4][BATCH][36];   // [wave][batch][gate-col], pad 36: 2-way max
    __shared__ float biasbuf[32];

    const int wg    = blockIdx.x;
    const int layer = (wg >= WGL) ? 1 : 0;
    const int wgl   = wg - layer * WGL;
    const int jbase = wgl * JPW;
    const int tid   = threadIdx.x;

    // ---- one-time: pre-convert x -> bf16 in ws (plain stores + release fence) ----
    if (use_xbf) {
        const size_t total4 = (size_t)BATCH * T_STEPS * HID / 4;
        unsigned long long* dst = (unsigned long long*)xbf;
        for (size_t idx = (size_t)wg * 256 + tid; idx < total4; idx += (size_t)NWG * 256) {
            float4 v = *(const float4*)(x_in + idx * 4);
            unsigned long long pk = (unsigned long long)f2bf(v.x)
                                  | ((unsigned long long)f2bf(v.y) << 16)
                                  | ((unsigned long long)f2bf(v.z) << 32)
                                  | ((unsigned long long)f2bf(v.w) << 48);
            dst[idx] = pk;
        }
        __builtin_amdgcn_fence(__ATOMIC_RELEASE, "agent");   // writeback L2 -> LLC
    }

    // ---- one-time: W slice -> LDS (bf16) ----
    {
        const int lr = tid >> 3;        // local gate row 0..31 (= gate*8 + jloc)
        const int g0 = tid & 7;
        const int gg = lr >> 3, jloc = lr & 7;
        const int r  = gg * HID + jbase + jloc;      // global gate row
        const float* srcA = Wih + ((size_t)layer * G4 + r) * HID;
        const float* srcB = Whh + ((size_t)layer * G4 + r) * HID;
        short* dstrow = &Wbuf[lr * APAD];
        #pragma unroll
        for (int i = 0; i < 16; ++i) {
            int g = g0 + 8 * i;         // 16B granule 0..127
            const float* src = (g < 64) ? (srcA + g * 8) : (srcB + (g - 64) * 8);
            float4 v0 = *(const float4*)(src);
            float4 v1 = *(const float4*)(src + 4);
            short8 p;
            p[0] = (short)f2bf(v0.x); p[1] = (short)f2bf(v0.y);
            p[2] = (short)f2bf(v0.z); p[3] = (short)f2bf(v0.w);
            p[4] = (short)f2bf(v1.x); p[5] = (short)f2bf(v1.y);
            p[6] = (short)f2bf(v1.z); p[7] = (short)f2bf(v1.w);
            *(short8*)(dstrow + g * 8) = p;
        }
    }
    if (tid < 32) {
        const int g = tid >> 3, jloc = tid & 7;
        const int r = g * HID + jbase + jloc;
        biasbuf[tid] = bih[(size_t)layer * G4 + r] + bhh[(size_t)layer * G4 + r];
    }

    const int m  = tid >> 3;
    const int jl = tid & 7;
    const int jg = jbase + jl;

    float creg = c0[((size_t)layer * BATCH + m) * HID + jg];

    // init h rings (sc1): readers at step s use slot (s+1)&1
    {
        unsigned hb = (unsigned)f2bf(h0[((size_t)layer * BATCH + m) * HID + jg]);
        unsigned ob = __shfl_xor(hb, 1);
        if ((tid & 1) == 0) {
            unsigned val = hb | (ob << 16);
            unsigned short* ring = (layer == 0) ? h1ring : h2ring;
            if (layer == 0) {
                unsigned* p = (unsigned*)(ring + ((size_t)1 * BATCH + m) * HID + (jg & ~1));
                __hip_atomic_store(p, val, __ATOMIC_RELAXED, __HIP_MEMORY_SCOPE_AGENT);
            } else {
                unsigned* p0 = (unsigned*)(ring + ((size_t)0 * BATCH + m) * HID + (jg & ~1));
                unsigned* p1 = (unsigned*)(ring + ((size_t)1 * BATCH + m) * HID + (jg & ~1));
                __hip_atomic_store(p0, val, __ATOMIC_RELAXED, __HIP_MEMORY_SCOPE_AGENT);
                __hip_atomic_store(p1, val, __ATOMIC_RELAXED, __HIP_MEMORY_SCOPE_AGENT);
            }
        }
    }

    g_arrive(flags, wg, 1u, tid);
    g_wait(flags, 1u, tid);
    // make other WGs' xbf conversion + ring init visible before first loads
    __builtin_amdgcn_fence(__ATOMIC_ACQUIRE, "agent");

    const int lane = tid & 63;
    const int wv   = tid >> 6;          // wave 0..3 -> K slice [wv*256, wv*256+256)
    const int hi   = lane >> 5;         // k sub-offset: +8*hi within each K=16 window
    const int arow = lane & 31;         // A: batch row; B: gate col (= Wbuf row)
    const int kq   = (wv & 1) * 256;    // k offset within the x-half or h-half
    const bool xw  = (wv < 2);          // wave covers A cols 0..511 (x part)

    const short* wrow = &Wbuf[arow * APAD + wv * 256 + hi * 8];

    short8 afr[16];                     // A fragments for this wave's K=256

#define PREFETCH_X(tt)                                                        \
    do {                                                                      \
        if (use_xbf) {                                                        \
            const short* bx = (const short*)xbf +                             \
                ((size_t)arow * T_STEPS + (tt)) * HID + kq + hi * 8;          \
            _Pragma("unroll")                                                 \
            for (int j = 0; j < 16; ++j)                                      \
                afr[j] = *(const short8*)(bx + j * 16);                       \
        } else {                                                              \
            const float* fx = x_in +                                          \
                ((size_t)arow * T_STEPS + (tt)) * HID + kq + hi * 8;          \
            _Pragma("unroll")                                                 \
            for (int j = 0; j < 16; ++j) {                                    \
                float4 v0 = *(const float4*)(fx + j * 16);                    \
                float4 v1 = *(const float4*)(fx + j * 16 + 4);                \
                short8 p;                                                     \
                p[0] = (short)f2bf(v0.x); p[1] = (short)f2bf(v0.y);           \
                p[2] = (short)f2bf(v0.z); p[3] = (short)f2bf(v0.w);           \
                p[4] = (short)f2bf(v1.x); p[5] = (short)f2bf(v1.y);           \
                p[6] = (short)f2bf(v1.z); p[7] = (short)f2bf(v1.w);           \
                afr[j] = p;                                                   \
            }                                                                 \
        }                                                                     \
    } while (0)

    // x(t=0) fragments for layer-0 x-waves (xbf immutable; values land in VGPRs)
    if (layer == 0 && xw) PREFETCH_X(0);

    for (int s = 0; s <= T_STEPS; ++s) {
        const int t = (layer == 0) ? s : s - 1;
        const bool active = (t >= 0) && (t < T_STEPS);
        float hv = 0.0f;
        if (active) {
            // acquire: invalidate clean L2 lines so plain ring loads see the
            // sc1-written h from the previous step.
            __builtin_amdgcn_fence(__ATOMIC_ACQUIRE, "agent");

            const int rs = (s + 1) & 1;

            // A fragments from global (skip layer-0 x-waves: prefetched)
            if (!(layer == 0 && xw)) {
                const unsigned short* ring =
                    (layer == 0) ? h1ring : (xw ? h1ring : h2ring);
                const short* base = (const short*)ring +
                    ((size_t)rs * BATCH + arow) * HID + kq + hi * 8;
                #pragma unroll
                for (int j = 0; j < 16; ++j)
                    afr[j] = *(const short8*)(base + j * 16);
            }

            f32x16 acc0, acc1;
            #pragma unroll
            for (int r = 0; r < 16; ++r) { acc0[r] = 0.0f; acc1[r] = 0.0f; }
            #pragma unroll
            for (int j = 0; j < 16; j += 2) {
                short8 b0 = *(const short8*)(wrow + j * 16);
                short8 b1 = *(const short8*)(wrow + j * 16 + 16);
                acc0 = __builtin_amdgcn_mfma_f32_32x32x16_bf16(afr[j],     b0, acc0, 0, 0, 0);
                acc1 = __builtin_amdgcn_mfma_f32_32x32x16_bf16(afr[j + 1], b1, acc1, 0, 0, 0);
            }
            // C/D layout (verified m74/m101): col=lane&31, row=(r&3)+8*(r>>2)+4*hi
            #pragma unroll
            for (int r = 0; r < 16; ++r)
                gatebuf[wv][(r & 3) + 8 * (r >> 2) + 4 * hi][arow] = acc0[r] + acc1[r];
            __syncthreads();

            float gi = gatebuf[0][m][jl]      + gatebuf[1][m][jl]
                     + gatebuf[2][m][jl]      + gatebuf[3][m][jl]      + biasbuf[jl];
            float gf = gatebuf[0][m][8 + jl]  + gatebuf[1][m][8 + jl]
                     + gatebuf[2][m][8 + jl]  + gatebuf[3][m][8 + jl]  + biasbuf[8 + jl];
            float gg = gatebuf[0][m][16 + jl] + gatebuf[1][m][16 + jl]
                     + gatebuf[2][m][16 + jl] + gatebuf[3][m][16 + jl] + biasbuf[16 + jl];
            float go = gatebuf[0][m][24 + jl] + gatebuf[1][m][24 + jl]
                     + gatebuf[2][m][24 + jl] + gatebuf[3][m][24 + jl] + biasbuf[24 + jl];
            float iv = sigm(gi), fv = sigm(gf), gv = ftanh(gg), ov = sigm(go);
            creg = fv * creg + iv * gv;
            hv = ov * ftanh(creg);

            // publish h (sc1, lane-paired u32) — ONLY writer of ring lines
            {
                const int wslot = s & 1;
                unsigned hb = (unsigned)f2bf(hv);
                unsigned ob = __shfl_xor(hb, 1);
                if ((tid & 1) == 0) {
                    unsigned val = hb | (ob << 16);
                    unsigned short* ringw = (layer == 0) ? h1ring : h2ring;
                    unsigned* p = (unsigned*)(ringw + ((size_t)wslot * BATCH + m) * HID + (jg & ~1));
                    __hip_atomic_store(p, val, __ATOMIC_RELAXED, __HIP_MEMORY_SCOPE_AGENT);
                }
            }
            if (t == T_STEPS - 1)
                out[H_OFF + ((size_t)layer * BATCH + m) * HID + jg] = hv;
        }

        const bool last = (s == T_STEPS);
        if (!last) g_arrive(flags, wg, (unsigned)(s + 2), tid);

        // ---- wait-window work (off the critical sync path) ----
        if (active && layer == 1)
            out[((size_t)m * T_STEPS + t) * HID + jg] = hv;     // [B,T,H], plain store
        if (layer == 0 && xw && active && t + 1 < T_STEPS)
            PREFETCH_X(t + 1);      // next x(t) fragments; in flight during poll

        if (!last) g_wait(flags, (unsigned)(s + 2), tid);
    }

    out[C_OFF + ((size_t)layer * BATCH + m) * HID + jg] = creg;
#undef PREFETCH_X
}

extern "C" void kernel_launch(void* const* d_in, const int* in_sizes, int n_in,
                              void* d_out, int out_size, void* d_ws, size_t ws_size,
                              hipStream_t stream) {
    const float* x   = (const float*)d_in[0];
    const float* h0  = (const float*)d_in[1];
    const float* c0  = (const float*)d_in[2];
    const float* Wih = (const float*)d_in[3];
    const float* Whh = (const float*)d_in[4];
    const float* bih = (const float*)d_in[5];
    const float* bhh = (const float*)d_in[6];
    float* out = (float*)d_out;

    unsigned char* ws = (unsigned char*)d_ws;
    unsigned* flags = (unsigned*)ws;                                   // 128 x 128B = 16KB
    unsigned short* h1ring = (unsigned short*)(ws + 16384);            // 64 KB
    unsigned short* h2ring = h1ring + 2 * BATCH * HID;                 // 64 KB
    unsigned short* xbf    = h2ring + 2 * BATCH * HID;                 // 32 MB (optional)

    const size_t xbf_need = 16384 + 2 * 64 * 1024 +
                            (size_t)BATCH * T_STEPS * HID * 2 + 4096;
    int use_xbf = (ws_size >= xbf_need) ? 1 : 0;

    hipLaunchKernelGGL(init_flags, dim3(1), dim3(256), 0, stream, flags);

    void* args[] = { (void*)&x, (void*)&h0, (void*)&c0, (void*)&Wih, (void*)&Whh,
                     (void*)&bih, (void*)&bhh, (void*)&out, (void*)&flags,
                     (void*)&h1ring, (void*)&h2ring, (void*)&xbf, (void*)&use_xbf };
    hipError_t e = hipLaunchCooperativeKernel((void*)lstm_persist, dim3(NWG), dim3(256),
                                              args, 0, stream);
    if (e != hipSuccess) {
        hipLaunchKernelGGL(lstm_persist, dim3(NWG), dim3(256), 0, stream,
                           x, h0, c0, Wih, Whh, bih, bhh, out, flags,
                           h1ring, h2ring, xbf, use_xbf);
    }
}

// Round 2
// 4652.065 us; speedup vs baseline: 1.7565x; 1.6758x over previous
//
#include <hip/hip_runtime.h>
#include <math.h>

// Problem constants
#define T_STEPS 1024
#define BATCH   32
#define HID     512
#define G4      2048          // 4*HID
#define KDIM    1024          // I + H (concat [x|h])
#define NWG     128           // total workgroups (64 per layer)
#define WGL     64            // WGs per layer
#define JPW     8             // h-columns owned per WG
#define APAD    1032          // Wbuf padded row stride (shorts)
#define FPAD    32            // flag stride in u32 (one 128B line per flag)

#define OUT_ELEMS   (BATCH * T_STEPS * HID)          // 16777216
#define H_OFF       OUT_ELEMS
#define C_OFF       (OUT_ELEMS + 2 * BATCH * HID)

typedef __attribute__((ext_vector_type(8)))  short short8;
typedef __attribute__((ext_vector_type(16))) float f32x16;

__device__ __forceinline__ unsigned short f2bf(float f) {
    union { float f; unsigned u; } v; v.f = f;
    unsigned r = v.u + 0x7fffu + ((v.u >> 16) & 1u);   // RNE
    return (unsigned short)(r >> 16);
}

__device__ __forceinline__ float sigm(float x)  { return 1.0f / (1.0f + __expf(-x)); }
__device__ __forceinline__ float ftanh(float x) { return 1.0f - 2.0f / (__expf(2.0f * x) + 1.0f); }

// Coherent 16B load: sc0 (bypass L1) + sc1 (bypass L2) -> reads LLC directly.
// This replaces the old {per-step agent-acquire fence (buffer_inv = full L2
// wipe, 128x/step) + plain loads} protocol for ring reads. Publisher already
// does agent-scope (write-through-LLC) stores + vmcnt(0) before the flag, so
// flag-visible => data-in-LLC => sc0sc1 read sees it. No invalidation needed,
// and the immutable xbf/weights now STAY cached in L2 across steps.
__device__ __forceinline__ short8 load_b128_llc(const void* p) {
    short8 r;
    asm volatile("global_load_dwordx4 %0, %1, off sc0 sc1"
                 : "=v"(r) : "v"(p));
    return r;
}

// ---- single-level direct-poll grid barrier ----
// Flags are agent-scope atomics, one per 128B line so 128 WGs x 128 lanes
// poll 128 distinct LLC lines (no slice hot-spot).
__device__ __forceinline__ void g_arrive(unsigned* flags, int wg, unsigned epoch, int tid) {
    asm volatile("s_waitcnt vmcnt(0)" ::: "memory");   // drain sc1 h-publishes
    __syncthreads();
    if (tid == 0)
        __hip_atomic_store(&flags[wg * FPAD], epoch, __ATOMIC_RELAXED, __HIP_MEMORY_SCOPE_AGENT);
}

__device__ __forceinline__ void g_wait(unsigned* flags, unsigned epoch, int tid) {
    if (tid < NWG) {
        while (__hip_atomic_load(&flags[tid * FPAD], __ATOMIC_RELAXED, __HIP_MEMORY_SCOPE_AGENT) < epoch)
            __builtin_amdgcn_s_sleep(1);
    }
    __syncthreads();
}

__global__ void init_flags(unsigned* flags) {
    for (int i = threadIdx.x; i < NWG * FPAD; i += 256) flags[i] = 0u;
}

// Per-WG GEMM: one 32x32 output tile (32 batch x 32 gate-rows), K=1024 split
// across the 4 waves (256 each), mfma_f32_32x32x16_bf16. A-fragments loaded
// DIRECTLY from global (xbf plain / h rings via sc0sc1-LLC) into VGPRs.
__global__ void __launch_bounds__(256, 1)
lstm_persist(const float* __restrict__ x_in,   // [32][1024][512]
             const float* __restrict__ h0,     // [2][32][512]
             const float* __restrict__ c0,     // [2][32][512]
             const float* __restrict__ Wih,    // [2][2048][512]
             const float* __restrict__ Whh,    // [2][2048][512]
             const float* __restrict__ bih,    // [2][2048]
             const float* __restrict__ bhh,    // [2][2048]
             float* __restrict__ out,
             unsigned* __restrict__ flags,
             unsigned short* __restrict__ h1ring,  // [2][32][512] bf16 (ws, sc1-written)
             unsigned short* __restrict__ h2ring,  // [2][32][512] bf16 (ws, sc1-written)
             unsigned short* __restrict__ xbf,     // [32][1024][512] bf16 (ws, plain)
             int use_xbf)
{
    __shared__ __attribute__((aligned(16))) short Wbuf[32 * APAD];
    __shared__ float gatebuf[4][BATCH][36];   // [wave][batch][gate-col]
    __shared__ float biasbuf[32];

    const int wg    = blockIdx.x;
    const int layer = (wg >= WGL) ? 1 : 0;
    const int wgl   = wg - layer * WGL;
    const int jbase = wgl * JPW;
    const int tid   = threadIdx.x;

    // ---- one-time: pre-convert x -> bf16 in ws (plain stores + release fence) ----
    if (use_xbf) {
        const size_t total4 = (size_t)BATCH * T_STEPS * HID / 4;
        unsigned long long* dst = (unsigned long long*)xbf;
        for (size_t idx = (size_t)wg * 256 + tid; idx < total4; idx += (size_t)NWG * 256) {
            float4 v = *(const float4*)(x_in + idx * 4);
            unsigned long long pk = (unsigned long long)f2bf(v.x)
                                  | ((unsigned long long)f2bf(v.y) << 16)
                                  | ((unsigned long long)f2bf(v.z) << 32)
                                  | ((unsigned long long)f2bf(v.w) << 48);
            dst[idx] = pk;
        }
        __builtin_amdgcn_fence(__ATOMIC_RELEASE, "agent");   // writeback L2 -> LLC
    }

    // ---- one-time: W slice -> LDS (bf16) ----
    {
        const int lr = tid >> 3;        // local gate row 0..31 (= gate*8 + jloc)
        const int g0 = tid & 7;
        const int gg = lr >> 3, jloc = lr & 7;
        const int r  = gg * HID + jbase + jloc;      // global gate row
        const float* srcA = Wih + ((size_t)layer * G4 + r) * HID;
        const float* srcB = Whh + ((size_t)layer * G4 + r) * HID;
        short* dstrow = &Wbuf[lr * APAD];
        #pragma unroll
        for (int i = 0; i < 16; ++i) {
            int g = g0 + 8 * i;         // 16B granule 0..127
            const float* src = (g < 64) ? (srcA + g * 8) : (srcB + (g - 64) * 8);
            float4 v0 = *(const float4*)(src);
            float4 v1 = *(const float4*)(src + 4);
            short8 p;
            p[0] = (short)f2bf(v0.x); p[1] = (short)f2bf(v0.y);
            p[2] = (short)f2bf(v0.z); p[3] = (short)f2bf(v0.w);
            p[4] = (short)f2bf(v1.x); p[5] = (short)f2bf(v1.y);
            p[6] = (short)f2bf(v1.z); p[7] = (short)f2bf(v1.w);
            *(short8*)(dstrow + g * 8) = p;
        }
    }
    if (tid < 32) {
        const int g = tid >> 3, jloc = tid & 7;
        const int r = g * HID + jbase + jloc;
        biasbuf[tid] = bih[(size_t)layer * G4 + r] + bhh[(size_t)layer * G4 + r];
    }

    const int m  = tid >> 3;
    const int jl = tid & 7;
    const int jg = jbase + jl;

    float creg = c0[((size_t)layer * BATCH + m) * HID + jg];

    // init h rings (sc1): readers at step s use slot (s+1)&1
    {
        unsigned hb = (unsigned)f2bf(h0[((size_t)layer * BATCH + m) * HID + jg]);
        unsigned ob = __shfl_xor(hb, 1);
        if ((tid & 1) == 0) {
            unsigned val = hb | (ob << 16);
            unsigned short* ring = (layer == 0) ? h1ring : h2ring;
            if (layer == 0) {
                unsigned* p = (unsigned*)(ring + ((size_t)1 * BATCH + m) * HID + (jg & ~1));
                __hip_atomic_store(p, val, __ATOMIC_RELAXED, __HIP_MEMORY_SCOPE_AGENT);
            } else {
                unsigned* p0 = (unsigned*)(ring + ((size_t)0 * BATCH + m) * HID + (jg & ~1));
                unsigned* p1 = (unsigned*)(ring + ((size_t)1 * BATCH + m) * HID + (jg & ~1));
                __hip_atomic_store(p0, val, __ATOMIC_RELAXED, __HIP_MEMORY_SCOPE_AGENT);
                __hip_atomic_store(p1, val, __ATOMIC_RELAXED, __HIP_MEMORY_SCOPE_AGENT);
            }
        }
    }

    g_arrive(flags, wg, 1u, tid);
    g_wait(flags, 1u, tid);
    // one-time acquire: make other WGs' xbf conversion visible to plain loads.
    // (This is the ONLY L2 invalidation after init -- none in the step loop.)
    __builtin_amdgcn_fence(__ATOMIC_ACQUIRE, "agent");

    const int lane = tid & 63;
    const int wv   = tid >> 6;          // wave 0..3 -> K slice [wv*256, wv*256+256)
    const int hi   = lane >> 5;         // k sub-offset: +8*hi within each K=16 window
    const int arow = lane & 31;         // A: batch row; B: gate col (= Wbuf row)
    const int kq   = (wv & 1) * 256;    // k offset within the x-half or h-half
    const bool xw  = (wv < 2);          // wave covers A cols 0..511 (x part)

    const short* wrow = &Wbuf[arow * APAD + wv * 256 + hi * 8];

    short8 afr[16];                     // A fragments for this wave's K=256

#define PREFETCH_X(tt)                                                        \
    do {                                                                      \
        if (use_xbf) {                                                        \
            const short* bx = (const short*)xbf +                             \
                ((size_t)arow * T_STEPS + (tt)) * HID + kq + hi * 8;          \
            _Pragma("unroll")                                                 \
            for (int j = 0; j < 16; ++j)                                      \
                afr[j] = *(const short8*)(bx + j * 16);                       \
        } else {                                                              \
            const float* fx = x_in +                                          \
                ((size_t)arow * T_STEPS + (tt)) * HID + kq + hi * 8;          \
            _Pragma("unroll")                                                 \
            for (int j = 0; j < 16; ++j) {                                    \
                float4 v0 = *(const float4*)(fx + j * 16);                    \
                float4 v1 = *(const float4*)(fx + j * 16 + 4);                \
                short8 p;                                                     \
                p[0] = (short)f2bf(v0.x); p[1] = (short)f2bf(v0.y);           \
                p[2] = (short)f2bf(v0.z); p[3] = (short)f2bf(v0.w);           \
                p[4] = (short)f2bf(v1.x); p[5] = (short)f2bf(v1.y);           \
                p[6] = (short)f2bf(v1.z); p[7] = (short)f2bf(v1.w);           \
                afr[j] = p;                                                   \
            }                                                                 \
        }                                                                     \
    } while (0)

    // x(t=0) fragments for layer-0 x-waves (xbf immutable; values land in VGPRs)
    if (layer == 0 && xw) PREFETCH_X(0);

    for (int s = 0; s <= T_STEPS; ++s) {
        const int t = (layer == 0) ? s : s - 1;
        const bool active = (t >= 0) && (t < T_STEPS);
        float hv = 0.0f;
        if (active) {
            const int rs = (s + 1) & 1;

            // A fragments from rings via direct-LLC loads (skip layer-0
            // x-waves: prefetched from L2-resident xbf in the wait window).
            if (!(layer == 0 && xw)) {
                const unsigned short* ring =
                    (layer == 0) ? h1ring : (xw ? h1ring : h2ring);
                const short* base = (const short*)ring +
                    ((size_t)rs * BATCH + arow) * HID + kq + hi * 8;
                #pragma unroll
                for (int j = 0; j < 16; ++j)
                    afr[j] = load_b128_llc(base + j * 16);
                asm volatile("s_waitcnt vmcnt(0)" ::: "memory");
                __builtin_amdgcn_sched_barrier(0);   // keep MFMAs below the wait
            }

            f32x16 acc0, acc1;
            #pragma unroll
            for (int r = 0; r < 16; ++r) { acc0[r] = 0.0f; acc1[r] = 0.0f; }
            #pragma unroll
            for (int j = 0; j < 16; j += 2) {
                short8 b0 = *(const short8*)(wrow + j * 16);
                short8 b1 = *(const short8*)(wrow + j * 16 + 16);
                acc0 = __builtin_amdgcn_mfma_f32_32x32x16_bf16(afr[j],     b0, acc0, 0, 0, 0);
                acc1 = __builtin_amdgcn_mfma_f32_32x32x16_bf16(afr[j + 1], b1, acc1, 0, 0, 0);
            }
            // C/D layout (verified m74/m101): col=lane&31, row=(r&3)+8*(r>>2)+4*hi
            #pragma unroll
            for (int r = 0; r < 16; ++r)
                gatebuf[wv][(r & 3) + 8 * (r >> 2) + 4 * hi][arow] = acc0[r] + acc1[r];
            __syncthreads();

            float gi = gatebuf[0][m][jl]      + gatebuf[1][m][jl]
                     + gatebuf[2][m][jl]      + gatebuf[3][m][jl]      + biasbuf[jl];
            float gf = gatebuf[0][m][8 + jl]  + gatebuf[1][m][8 + jl]
                     + gatebuf[2][m][8 + jl]  + gatebuf[3][m][8 + jl]  + biasbuf[8 + jl];
            float gg = gatebuf[0][m][16 + jl] + gatebuf[1][m][16 + jl]
                     + gatebuf[2][m][16 + jl] + gatebuf[3][m][16 + jl] + biasbuf[16 + jl];
            float go = gatebuf[0][m][24 + jl] + gatebuf[1][m][24 + jl]
                     + gatebuf[2][m][24 + jl] + gatebuf[3][m][24 + jl] + biasbuf[24 + jl];
            float iv = sigm(gi), fv = sigm(gf), gv = ftanh(gg), ov = sigm(go);
            creg = fv * creg + iv * gv;
            hv = ov * ftanh(creg);

            // publish h (sc1, lane-paired u32) — ONLY writer of ring lines
            {
                const int wslot = s & 1;
                unsigned hb = (unsigned)f2bf(hv);
                unsigned ob = __shfl_xor(hb, 1);
                if ((tid & 1) == 0) {
                    unsigned val = hb | (ob << 16);
                    unsigned short* ringw = (layer == 0) ? h1ring : h2ring;
                    unsigned* p = (unsigned*)(ringw + ((size_t)wslot * BATCH + m) * HID + (jg & ~1));
                    __hip_atomic_store(p, val, __ATOMIC_RELAXED, __HIP_MEMORY_SCOPE_AGENT);
                }
            }
            if (t == T_STEPS - 1)
                out[H_OFF + ((size_t)layer * BATCH + m) * HID + jg] = hv;
        }

        const bool last = (s == T_STEPS);
        if (!last) g_arrive(flags, wg, (unsigned)(s + 2), tid);

        // ---- wait-window work (off the critical sync path) ----
        if (active && layer == 1)
            out[((size_t)m * T_STEPS + t) * HID + jg] = hv;     // [B,T,H], plain store
        if (layer == 0 && xw && active && t + 1 < T_STEPS)
            PREFETCH_X(t + 1);      // next x(t) fragments; in flight during poll

        if (!last) g_wait(flags, (unsigned)(s + 2), tid);
    }

    out[C_OFF + ((size_t)layer * BATCH + m) * HID + jg] = creg;
#undef PREFETCH_X
}

extern "C" void kernel_launch(void* const* d_in, const int* in_sizes, int n_in,
                              void* d_out, int out_size, void* d_ws, size_t ws_size,
                              hipStream_t stream) {
    const float* x   = (const float*)d_in[0];
    const float* h0  = (const float*)d_in[1];
    const float* c0  = (const float*)d_in[2];
    const float* Wih = (const float*)d_in[3];
    const float* Whh = (const float*)d_in[4];
    const float* bih = (const float*)d_in[5];
    const float* bhh = (const float*)d_in[6];
    float* out = (float*)d_out;

    unsigned char* ws = (unsigned char*)d_ws;
    unsigned* flags = (unsigned*)ws;                                   // 128 x 128B = 16KB
    unsigned short* h1ring = (unsigned short*)(ws + 16384);            // 64 KB
    unsigned short* h2ring = h1ring + 2 * BATCH * HID;                 // 64 KB
    unsigned short* xbf    = h2ring + 2 * BATCH * HID;                 // 32 MB (optional)

    const size_t xbf_need = 16384 + 2 * 64 * 1024 +
                            (size_t)BATCH * T_STEPS * HID * 2 + 4096;
    int use_xbf = (ws_size >= xbf_need) ? 1 : 0;

    hipLaunchKernelGGL(init_flags, dim3(1), dim3(256), 0, stream, flags);

    void* args[] = { (void*)&x, (void*)&h0, (void*)&c0, (void*)&Wih, (void*)&Whh,
                     (void*)&bih, (void*)&bhh, (void*)&out, (void*)&flags,
                     (void*)&h1ring, (void*)&h2ring, (void*)&xbf, (void*)&use_xbf };
    hipError_t e = hipLaunchCooperativeKernel((void*)lstm_persist, dim3(NWG), dim3(256),
                                              args, 0, stream);
    if (e != hipSuccess) {
        hipLaunchKernelGGL(lstm_persist, dim3(NWG), dim3(256), 0, stream,
                           x, h0, c0, Wih, Whh, bih, bhh, out, flags,
                           h1ring, h2ring, xbf, use_xbf);
    }
}

// Round 4
// 4267.197 us; speedup vs baseline: 1.9149x; 1.0902x over previous
//
#include <hip/hip_runtime.h>
#include <math.h>

// Problem constants
#define T_STEPS 1024
#define BATCH   32
#define HID     512
#define G4      2048          // 4*HID
#define NWG     128           // total workgroups (64 per layer)
#define WGL     64            // WGs per layer
#define JPW     8             // h-columns owned per WG
#define FPAD    32            // flag stride in u32 (one 128B line per flag)
#define RD      8             // h1 cross-layer ring depth (slots)

// workspace layout (bytes)
#define WS_FLAGS 0            // 128 flags x 128B = 16KB
#define WS_H1    16384        // h1 ring: 8 * 32 * 512 * 2B = 256KB
#define WS_H2    278528       // h2 ring: 2 * 32 * 512 * 2B = 64KB
#define WS_XBF   344064       // x in bf16: 32MB (optional)

#define OUT_ELEMS (BATCH * T_STEPS * HID)
#define H_OFF OUT_ELEMS
#define C_OFF (OUT_ELEMS + 2 * BATCH * HID)

typedef __attribute__((ext_vector_type(8)))  short short8;
typedef __attribute__((ext_vector_type(16))) float f32x16;

__device__ __forceinline__ unsigned short f2bf(float f) {
    union { float f; unsigned u; } v; v.f = f;
    unsigned r = v.u + 0x7fffu + ((v.u >> 16) & 1u);   // RNE
    return (unsigned short)(r >> 16);
}
__device__ __forceinline__ float sigm(float x)  { return 1.0f / (1.0f + __expf(-x)); }
__device__ __forceinline__ float ftanh(float x) { return 1.0f - 2.0f / (__expf(2.0f * x) + 1.0f); }

// Coherent 16B load: sc0+sc1 -> reads LLC directly (proven R2 protocol).
// Publisher does agent-scope (write-through-LLC) stores + vmcnt(0) before its
// flag, so flag-visible => data-in-LLC => this load sees it. No L2 inv needed;
// immutable xbf/weights stay L2-cached.
__device__ __forceinline__ short8 ld_llc(const void* p) {
    short8 r;
    asm volatile("global_load_dwordx4 %0, %1, off sc0 sc1" : "=v"(r) : "v"(p));
    return r;
}

__device__ __forceinline__ void g_arrive(unsigned* flags, int wg, unsigned epoch, int tid) {
    asm volatile("s_waitcnt vmcnt(0)" ::: "memory");   // drain sc1 h-publishes
    __syncthreads();
    if (tid == 0)
        __hip_atomic_store(&flags[wg * FPAD], epoch, __ATOMIC_RELAXED, __HIP_MEMORY_SCOPE_AGENT);
}

__device__ __forceinline__ void poll_ge(const unsigned* p, unsigned epoch) {
    while (__hip_atomic_load(p, __ATOMIC_RELAXED, __HIP_MEMORY_SCOPE_AGENT) < epoch)
        __builtin_amdgcn_s_sleep(1);
}

__global__ void init_flags(unsigned* flags) {
    for (int i = threadIdx.x; i < NWG * FPAD; i += 256) flags[i] = 0u;
}

// Per-WG GEMM: one 32x32 output tile (32 batch x 32 gate-rows), K=1024 split
// across 4 waves (256 each), mfma_f32_32x32x16_bf16. A-fragments direct from
// global (xbf plain / h rings via sc0sc1-LLC). B (weights) live in VGPRs.
// Layers are DECOUPLED: per-layer 64-WG barriers; cross-layer h1 flows through
// an 8-deep LLC ring with slack (L1 at pipeline offset t = s-2).
__global__ void __launch_bounds__(256, 1)
lstm_persist(const float* __restrict__ x_in,   // [32][1024][512]
             const float* __restrict__ h0,     // [2][32][512]
             const float* __restrict__ c0,     // [2][32][512]
             const float* __restrict__ Wih,    // [2][2048][512]
             const float* __restrict__ Whh,    // [2][2048][512]
             const float* __restrict__ bih,    // [2][2048]
             const float* __restrict__ bhh,    // [2][2048]
             float* __restrict__ out,
             unsigned char* __restrict__ ws,
             int use_xbf)
{
    __shared__ float gatebuf[4][BATCH][36];
    __shared__ float biasbuf[32];

    const int wg    = blockIdx.x;
    const int layer = (wg >= WGL) ? 1 : 0;
    const int wgl   = wg - layer * WGL;
    const int jbase = wgl * JPW;
    const int tid   = threadIdx.x;

    unsigned* flags = (unsigned*)(ws + WS_FLAGS);
    unsigned short* h1ring = (unsigned short*)(ws + WS_H1);   // 8-slot, LLC
    unsigned short* h2ring = (unsigned short*)(ws + WS_H2);   // 2-slot, LLC
    unsigned short* xbf    = (unsigned short*)(ws + WS_XBF);

    // ---- one-time: x -> bf16 in ws (plain stores + release fence) ----
    if (use_xbf) {
        const size_t total4 = (size_t)BATCH * T_STEPS * HID / 4;
        unsigned long long* dst = (unsigned long long*)xbf;
        for (size_t idx = (size_t)wg * 256 + tid; idx < total4; idx += (size_t)NWG * 256) {
            float4 v = *(const float4*)(x_in + idx * 4);
            unsigned long long pk = (unsigned long long)f2bf(v.x)
                                  | ((unsigned long long)f2bf(v.y) << 16)
                                  | ((unsigned long long)f2bf(v.z) << 32)
                                  | ((unsigned long long)f2bf(v.w) << 48);
            dst[idx] = pk;
        }
        __builtin_amdgcn_fence(__ATOMIC_RELEASE, "agent");   // writeback L2 -> LLC
    }

    if (tid < 32) {
        const int g = tid >> 3, jloc = tid & 7;
        const int r = g * HID + jbase + jloc;
        biasbuf[tid] = bih[(size_t)layer * G4 + r] + bhh[(size_t)layer * G4 + r];
    }

    const int lane = tid & 63;
    const int wv   = tid >> 6;          // wave 0..3 = K quarter
    const int hi   = lane >> 5;
    const int l31  = lane & 31;
    const int kb   = (wv & 1) * 256;    // k offset within the 512-wide half

    // ---- weights -> VGPRs (loop-invariant B fragments; no Wbuf, no ds_read) ----
    short8 bW[16];
    {
        const float* Wsel = ((wv < 2) ? Wih : Whh) + (size_t)layer * G4 * HID;
        const int r = (l31 >> 3) * HID + jbase + (l31 & 7);   // gate row for col l31
        const float* wr = Wsel + (size_t)r * HID + kb + hi * 8;
        #pragma unroll
        for (int j = 0; j < 16; ++j) {
            float4 v0 = *(const float4*)(wr + j * 16);
            float4 v1 = *(const float4*)(wr + j * 16 + 4);
            short8 p;
            p[0]=(short)f2bf(v0.x); p[1]=(short)f2bf(v0.y); p[2]=(short)f2bf(v0.z); p[3]=(short)f2bf(v0.w);
            p[4]=(short)f2bf(v1.x); p[5]=(short)f2bf(v1.y); p[6]=(short)f2bf(v1.z); p[7]=(short)f2bf(v1.w);
            bW[j] = p;
        }
    }

    const int m  = tid >> 3;
    const int jl = tid & 7;
    const int jg = jbase + jl;

    float creg = c0[((size_t)layer * BATCH + m) * HID + jg];

    // ---- seed rings (agent-scope): L0 reads h1(-1)=h0 from slot 7 at s=0;
    //      L1 reads h2(-1)=h0 from slot (s+1)&1 = 1 at its first active s=2. ----
    {
        unsigned hb = (unsigned)f2bf(h0[((size_t)layer * BATCH + m) * HID + jg]);
        unsigned ob = __shfl_xor(hb, 1);
        if ((tid & 1) == 0) {
            unsigned val = hb | (ob << 16);
            if (layer == 0) {
                unsigned* p = (unsigned*)(h1ring + ((size_t)7 * BATCH + m) * HID + (jg & ~1));
                __hip_atomic_store(p, val, __ATOMIC_RELAXED, __HIP_MEMORY_SCOPE_AGENT);
            } else {
                unsigned* p0 = (unsigned*)(h2ring + ((size_t)0 * BATCH + m) * HID + (jg & ~1));
                unsigned* p1 = (unsigned*)(h2ring + ((size_t)1 * BATCH + m) * HID + (jg & ~1));
                __hip_atomic_store(p0, val, __ATOMIC_RELAXED, __HIP_MEMORY_SCOPE_AGENT);
                __hip_atomic_store(p1, val, __ATOMIC_RELAXED, __HIP_MEMORY_SCOPE_AGENT);
            }
        }
    }

    // ---- seed barrier: GLOBAL once (xbf + seed visibility), epoch 1 ----
    g_arrive(flags, wg, 1u, tid);
    if (tid < NWG) poll_ge(flags + tid * FPAD, 1u);
    __syncthreads();
    __builtin_amdgcn_fence(__ATOMIC_ACQUIRE, "agent");   // one-time inv for xbf plain loads

    const unsigned* fL0 = flags;
    const unsigned* fL1 = flags + WGL * FPAD;

    short8 afr[16];

#define PREFX(tt)                                                             \
    do {                                                                      \
        if (use_xbf) {                                                        \
            const short* bx = (const short*)xbf +                             \
                ((size_t)l31 * T_STEPS + (tt)) * HID + kb + hi * 8;           \
            _Pragma("unroll")                                                 \
            for (int j = 0; j < 16; ++j)                                      \
                afr[j] = *(const short8*)(bx + j * 16);                       \
        } else {                                                              \
            const float* fx = x_in +                                          \
                ((size_t)l31 * T_STEPS + (tt)) * HID + kb + hi * 8;           \
            _Pragma("unroll")                                                 \
            for (int j = 0; j < 16; ++j) {                                    \
                float4 v0 = *(const float4*)(fx + j * 16);                    \
                float4 v1 = *(const float4*)(fx + j * 16 + 4);                \
                short8 p;                                                     \
                p[0]=(short)f2bf(v0.x); p[1]=(short)f2bf(v0.y);               \
                p[2]=(short)f2bf(v0.z); p[3]=(short)f2bf(v0.w);               \
                p[4]=(short)f2bf(v1.x); p[5]=(short)f2bf(v1.y);               \
                p[6]=(short)f2bf(v1.z); p[7]=(short)f2bf(v1.w);               \
                afr[j] = p;                                                   \
            }                                                                 \
        }                                                                     \
    } while (0)

    if (layer == 0 && wv < 2) PREFX(0);

    // L0: t = s         (active s = 0..1023)
    // L1: t = s - 2     (active s = 2..1025); h1(t) prefetched in wait window
    const int SE = T_STEPS + 2;                                   // 1026
    for (int s = 0; s <= SE; ++s) {
        const int t = (layer == 0) ? s : s - 2;
        const bool active = (t >= 0) && (t < T_STEPS);
        const bool last = (s == SE);
        float hv = 0.0f;

        if (active) {
            if (wv >= 2) {     // h-half: own-layer recurrence, fresh from LLC ring
                const unsigned short* ring = (layer == 0) ? h1ring : h2ring;
                const size_t slot = (layer == 0) ? (size_t)((s - 1) & 7)
                                                 : (size_t)((s + 1) & 1);
                const short* base = (const short*)ring +
                    (slot * BATCH + l31) * HID + kb + hi * 8;
                #pragma unroll
                for (int j = 0; j < 16; ++j) afr[j] = ld_llc(base + j * 16);
            }
            asm volatile("s_waitcnt vmcnt(0)" ::: "memory");
            __builtin_amdgcn_sched_barrier(0);   // keep MFMAs below the wait

            f32x16 acc0, acc1;
            #pragma unroll
            for (int r = 0; r < 16; ++r) { acc0[r] = 0.f; acc1[r] = 0.f; }
            #pragma unroll
            for (int j = 0; j < 16; j += 2) {
                acc0 = __builtin_amdgcn_mfma_f32_32x32x16_bf16(afr[j],     bW[j],     acc0, 0, 0, 0);
                acc1 = __builtin_amdgcn_mfma_f32_32x32x16_bf16(afr[j + 1], bW[j + 1], acc1, 0, 0, 0);
            }
            // C/D layout: col=lane&31, row=(r&3)+8*(r>>2)+4*hi  [verified m74/m101]
            #pragma unroll
            for (int r = 0; r < 16; ++r)
                gatebuf[wv][(r & 3) + 8 * (r >> 2) + 4 * hi][l31] = acc0[r] + acc1[r];
            __syncthreads();

            float gi = gatebuf[0][m][jl]      + gatebuf[1][m][jl]
                     + gatebuf[2][m][jl]      + gatebuf[3][m][jl]      + biasbuf[jl];
            float gf = gatebuf[0][m][8  + jl] + gatebuf[1][m][8  + jl]
                     + gatebuf[2][m][8  + jl] + gatebuf[3][m][8  + jl] + biasbuf[8  + jl];
            float gg = gatebuf[0][m][16 + jl] + gatebuf[1][m][16 + jl]
                     + gatebuf[2][m][16 + jl] + gatebuf[3][m][16 + jl] + biasbuf[16 + jl];
            float go = gatebuf[0][m][24 + jl] + gatebuf[1][m][24 + jl]
                     + gatebuf[2][m][24 + jl] + gatebuf[3][m][24 + jl] + biasbuf[24 + jl];
            float iv = sigm(gi), fv = sigm(gf), gv = ftanh(gg), ov = sigm(go);
            creg = fv * creg + iv * gv;
            hv = ov * ftanh(creg);

            // publish h (agent-scope, lane-paired u32) — ONLY writer of ring lines
            {
                unsigned hb = (unsigned)f2bf(hv);
                unsigned ob = __shfl_xor(hb, 1);
                if ((tid & 1) == 0) {
                    unsigned val = hb | (ob << 16);
                    unsigned* p;
                    if (layer == 0)
                        p = (unsigned*)(h1ring + ((size_t)(s & 7) * BATCH + m) * HID + (jg & ~1));
                    else
                        p = (unsigned*)(h2ring + ((size_t)(s & 1) * BATCH + m) * HID + (jg & ~1));
                    __hip_atomic_store(p, val, __ATOMIC_RELAXED, __HIP_MEMORY_SCOPE_AGENT);
                }
            }
            if (t == T_STEPS - 1)
                out[H_OFF + ((size_t)layer * BATCH + m) * HID + jg] = hv;
        }

        if (!last) {
            g_arrive(flags, wg, (unsigned)(s + 2), tid);   // post own epoch FIRST

            // ---- wait-window work (off the critical sync path) ----
            if (layer == 1) {
                if (active)
                    out[((size_t)m * T_STEPS + t) * HID + jg] = hv;   // [B,T,H]
                if (wv < 2 && s >= 1 && s <= T_STEPS) {
                    // prefetch h1(s-1) for step s+1 (t=s-1): need all L0 >= s+1
                    // (L0 posted s+1 at end of its step s-1 -> ~1 step slack)
                    poll_ge(fL0 + lane * FPAD, (unsigned)(s + 1));
                    const short* base = (const short*)h1ring +
                        ((size_t)((s - 1) & 7) * BATCH + l31) * HID + kb + hi * 8;
                    #pragma unroll
                    for (int j = 0; j < 16; ++j) afr[j] = ld_llc(base + j * 16);
                }
                if (wv == 3)                       // own-layer barrier
                    poll_ge(fL1 + lane * FPAD, (unsigned)(s + 2));
            } else {
                if (wv < 2 && active && t + 1 < T_STEPS) PREFX(t + 1);
                if (wv == 2 && s >= 7)             // WAR: step s+1 publish kills
                    poll_ge(fL1 + lane * FPAD, (unsigned)(s - 3));   // h1(s-7); ~5 steps slack
                if (wv == 3)                       // own-layer barrier
                    poll_ge(fL0 + lane * FPAD, (unsigned)(s + 2));
            }
            __syncthreads();
        }
    }

    out[C_OFF + ((size_t)layer * BATCH + m) * HID + jg] = creg;
#undef PREFX
}

extern "C" void kernel_launch(void* const* d_in, const int* in_sizes, int n_in,
                              void* d_out, int out_size, void* d_ws, size_t ws_size,
                              hipStream_t stream) {
    const float* x   = (const float*)d_in[0];
    const float* h0  = (const float*)d_in[1];
    const float* c0  = (const float*)d_in[2];
    const float* Wih = (const float*)d_in[3];
    const float* Whh = (const float*)d_in[4];
    const float* bih = (const float*)d_in[5];
    const float* bhh = (const float*)d_in[6];
    float* out = (float*)d_out;
    unsigned char* ws = (unsigned char*)d_ws;

    const size_t xbf_need = (size_t)WS_XBF + (size_t)BATCH * T_STEPS * HID * 2;
    int use_xbf = (ws_size >= xbf_need) ? 1 : 0;

    hipLaunchKernelGGL(init_flags, dim3(1), dim3(256), 0, stream, (unsigned*)ws);

    void* args[] = { (void*)&x, (void*)&h0, (void*)&c0, (void*)&Wih, (void*)&Whh,
                     (void*)&bih, (void*)&bhh, (void*)&out, (void*)&ws, (void*)&use_xbf };
    hipError_t e = hipLaunchCooperativeKernel((void*)lstm_persist, dim3(NWG), dim3(256),
                                              args, 0, stream);
    if (e != hipSuccess) {
        hipLaunchKernelGGL(lstm_persist, dim3(NWG), dim3(256), 0, stream,
                           x, h0, c0, Wih, Whh, bih, bhh, out, ws, use_xbf);
    }
}